// Round 3
// baseline (171.244 us; speedup 1.0000x reference)
//
#include <hip/hip_runtime.h>
#include <hip/hip_fp16.h>

#define D_FEAT 128
#define THRESH 0.01f
#define EPS_F  1e-8f

typedef _Float16 half2_t __attribute__((ext_vector_type(2)));

// ---------------------------------------------------------------------------
// Exact helpers: bit-exact replication of numpy's fp32 pipeline
// (8-accumulator pairwise sum). Proven absmax=0 in rounds 1-2.
// ---------------------------------------------------------------------------

// Fully-scalar exact path for one arbitrary edge (mirror-structure fallback).
__device__ float edge_out_scalar(const float* __restrict__ feat,
                                 float w, int s, int d) {
#pragma clang fp contract(off)
    const float* fs = feat + (size_t)s * D_FEAT;
    const float* fd = feat + (size_t)d * D_FEAT;
    float r[8], rs[8], rd[8];
#pragma unroll
    for (int j = 0; j < 8; ++j) {
        float a = fs[j], b = fd[j];
        r[j]  = a * b;
        rs[j] = a * a;
        rd[j] = b * b;
    }
    for (int k = 1; k < 16; ++k) {
#pragma unroll
        for (int j = 0; j < 8; ++j) {
            float a = fs[8 * k + j], b = fd[8 * k + j];
            r[j]  = r[j]  + a * b;
            rs[j] = rs[j] + a * a;
            rd[j] = rd[j] + b * b;
        }
    }
    float inner = ((r[0]  + r[1])  + (r[2]  + r[3]))  + ((r[4]  + r[5])  + (r[6]  + r[7]));
    float ss    = ((rs[0] + rs[1]) + (rs[2] + rs[3])) + ((rs[4] + rs[5]) + (rs[6] + rs[7]));
    float dd    = ((rd[0] + rd[1]) + (rd[2] + rd[3])) + ((rd[4] + rd[5]) + (rd[6] + rd[7]));
    float ns = __fsqrt_rn(ss);
    float nd = __fsqrt_rn(dd);
    float denom = ns * nd + EPS_F;
    float sim = inner / denom;
    float keep = (sim >= THRESH) ? 1.0f : 0.0f;
    float diag = (s == d) ? 2.0f : 1.0f;
    return (w * keep) * diag;
}

// Two-lane exact sim (dot + both norms): used by the ws-too-small fallback.
__device__ __forceinline__ float exact_sim_pairlanes(const float* __restrict__ feat,
                                                     int src, int dst, int h) {
#pragma clang fp contract(off)
    const float4* fs = (const float4*)(feat + (size_t)src * D_FEAT);
    const float4* fd = (const float4*)(feat + (size_t)dst * D_FEAT);
    float r[4], rs[4], rd[4];
    {
        float4 a = fs[h];
        float4 b = fd[h];
        r[0]  = a.x * b.x; r[1]  = a.y * b.y; r[2]  = a.z * b.z; r[3]  = a.w * b.w;
        rs[0] = a.x * a.x; rs[1] = a.y * a.y; rs[2] = a.z * a.z; rs[3] = a.w * a.w;
        rd[0] = b.x * b.x; rd[1] = b.y * b.y; rd[2] = b.z * b.z; rd[3] = b.w * b.w;
    }
#pragma unroll
    for (int k = 1; k < 16; ++k) {
        float4 a = fs[2 * k + h];
        float4 b = fd[2 * k + h];
        r[0]  = r[0]  + a.x * b.x;  r[1]  = r[1]  + a.y * b.y;
        r[2]  = r[2]  + a.z * b.z;  r[3]  = r[3]  + a.w * b.w;
        rs[0] = rs[0] + a.x * a.x;  rs[1] = rs[1] + a.y * a.y;
        rs[2] = rs[2] + a.z * a.z;  rs[3] = rs[3] + a.w * a.w;
        rd[0] = rd[0] + b.x * b.x;  rd[1] = rd[1] + b.y * b.y;
        rd[2] = rd[2] + b.z * b.z;  rd[3] = rd[3] + b.w * b.w;
    }
    float A  = (r[0]  + r[1])  + (r[2]  + r[3]);
    float As = (rs[0] + rs[1]) + (rs[2] + rs[3]);
    float Ad = (rd[0] + rd[1]) + (rd[2] + rd[3]);

    float inner = A  + __shfl_xor(A, 1, 64);
    float ssE   = As + __shfl_xor(As, 1, 64);
    float ddE   = Ad + __shfl_xor(Ad, 1, 64);

    float ns    = __fsqrt_rn(ssE);
    float nd    = __fsqrt_rn(ddE);
    float den   = ns * nd + EPS_F;
    return inner / den;
}

// Two-lane exact INNER only (norms come from the precomputed exact table).
__device__ __forceinline__ float exact_inner_pairlanes(const float* __restrict__ feat,
                                                       int src, int dst, int h) {
#pragma clang fp contract(off)
    const float4* fs = (const float4*)(feat + (size_t)src * D_FEAT);
    const float4* fd = (const float4*)(feat + (size_t)dst * D_FEAT);
    float r[4];
    {
        float4 a = fs[h];
        float4 b = fd[h];
        r[0] = a.x * b.x; r[1] = a.y * b.y; r[2] = a.z * b.z; r[3] = a.w * b.w;
    }
#pragma unroll
    for (int k = 1; k < 16; ++k) {
        float4 a = fs[2 * k + h];
        float4 b = fd[2 * k + h];
        r[0] = r[0] + a.x * b.x;  r[1] = r[1] + a.y * b.y;
        r[2] = r[2] + a.z * b.z;  r[3] = r[3] + a.w * b.w;
    }
    float A = (r[0] + r[1]) + (r[2] + r[3]);
    return A + __shfl_xor(A, 1, 64);
}

// ---------------------------------------------------------------------------
// Fallback kernel (ws too small / odd feature count): round-1 proven path.
// ---------------------------------------------------------------------------
__global__ __launch_bounds__(256) void jaccard_edge_kernel(
    const int* __restrict__ ei, const float* __restrict__ w,
    const float* __restrict__ feat, float* __restrict__ out,
    int P, int E)
{
    int t    = blockIdx.x * blockDim.x + threadIdx.x;
    int pair = t >> 1;
    int half = t & 1;
    if (pair >= P) return;

    int src = ei[pair];
    int dst = ei[E + pair];

    float sim  = exact_sim_pairlanes(feat, src, dst, half);
    float keep = (sim >= THRESH) ? 1.0f : 0.0f;

    if (half == 0) {
        float diag = (src == dst) ? 2.0f : 1.0f;
        out[pair] = (w[pair] * keep) * diag;
        int m = P + pair;
        if (m < E) {
            int s2 = ei[m];
            int d2 = ei[E + m];
            if (s2 == dst && d2 == src) out[m] = (w[m] * keep) * diag;
            else                        out[m] = edge_out_scalar(feat, w[m], s2, d2);
        }
    }
}

// ---------------------------------------------------------------------------
// Pass A: fused fp16 convert + EXACT numpy norm per node. 2 lanes per node,
// lane h holds numpy accumulator classes [4h,4h+4): element i = 8k+4h+m lives
// in float4-chunk (2k+h). Sequential k == numpy accumulation order; cross-lane
// shfl_xor(1) add == numpy's final pairwise combine (IEEE-commutative).
// ---------------------------------------------------------------------------
__global__ __launch_bounds__(256) void norm_convert_kernel(
    const float* __restrict__ feat, __half* __restrict__ hfeat,
    float* __restrict__ nrm, int nNodes)
{
#pragma clang fp contract(off)
    int t = blockIdx.x * blockDim.x + threadIdx.x;
    int node = t >> 1;
    int h    = t & 1;
    if (node >= nNodes) return;

    const float4* fs  = (const float4*)(feat + (size_t)node * D_FEAT);
    uint2*        hro = (uint2*)(hfeat + (size_t)node * D_FEAT);

    float rs[4];
    {
        float4 a = fs[h];
        rs[0] = a.x * a.x; rs[1] = a.y * a.y; rs[2] = a.z * a.z; rs[3] = a.w * a.w;
        __half2 h0 = __floats2half2_rn(a.x, a.y);
        __half2 h1 = __floats2half2_rn(a.z, a.w);
        uint2 o;
        o.x = __builtin_bit_cast(unsigned int, h0);
        o.y = __builtin_bit_cast(unsigned int, h1);
        hro[h] = o;
    }
#pragma unroll
    for (int k = 1; k < 16; ++k) {
        float4 a = fs[2 * k + h];
        rs[0] = rs[0] + a.x * a.x;  rs[1] = rs[1] + a.y * a.y;
        rs[2] = rs[2] + a.z * a.z;  rs[3] = rs[3] + a.w * a.w;
        __half2 h0 = __floats2half2_rn(a.x, a.y);
        __half2 h1 = __floats2half2_rn(a.z, a.w);
        uint2 o;
        o.x = __builtin_bit_cast(unsigned int, h0);
        o.y = __builtin_bit_cast(unsigned int, h1);
        hro[2 * k + h] = o;
    }
    float As = (rs[0] + rs[1]) + (rs[2] + rs[3]);
    float ss = As + __shfl_xor(As, 1, 64);
    if (h == 0) nrm[node] = __fsqrt_rn(ss);
}

// ---------------------------------------------------------------------------
// Pass B: fp16 gather + v_dot2_f32_f16 dot; exact norms from table; rigorous
// Cauchy-Schwarz bound (near-constant 1.1e-3); exact fp32 recompute for
// borderline pairs (~1%). 2 lanes/pair: lane h reads uint4 chunks {2k+h} of
// both rows -> 16 outstanding 16B loads per lane.
// ---------------------------------------------------------------------------
__device__ __forceinline__ float dot8_f16(uint4 ua, uint4 ub, float acc) {
    acc = __builtin_amdgcn_fdot2(__builtin_bit_cast(half2_t, ua.x),
                                 __builtin_bit_cast(half2_t, ub.x), acc, false);
    acc = __builtin_amdgcn_fdot2(__builtin_bit_cast(half2_t, ua.y),
                                 __builtin_bit_cast(half2_t, ub.y), acc, false);
    acc = __builtin_amdgcn_fdot2(__builtin_bit_cast(half2_t, ua.z),
                                 __builtin_bit_cast(half2_t, ub.z), acc, false);
    acc = __builtin_amdgcn_fdot2(__builtin_bit_cast(half2_t, ua.w),
                                 __builtin_bit_cast(half2_t, ub.w), acc, false);
    return acc;
}

__global__ __launch_bounds__(256) void jaccard_edge_f16n_kernel(
    const int* __restrict__ ei, const float* __restrict__ w,
    const float* __restrict__ feat, const __half* __restrict__ hfeat,
    const float* __restrict__ nrm, float* __restrict__ out, int P, int E)
{
#pragma clang fp contract(off)
    int t    = blockIdx.x * blockDim.x + threadIdx.x;
    int pair = t >> 1;
    int h    = t & 1;
    if (pair >= P) return;

    int src = ei[pair];
    int dst = ei[E + pair];

    const uint4* ha = (const uint4*)(hfeat + (size_t)src * D_FEAT);
    const uint4* hb = (const uint4*)(hfeat + (size_t)dst * D_FEAT);

    uint4 A[8], B[8];
#pragma unroll
    for (int k = 0; k < 8; ++k) {
        A[k] = ha[2 * k + h];
        B[k] = hb[2 * k + h];
    }
    float na = nrm[src];
    float nb = nrm[dst];

    float d = 0.f;
#pragma unroll
    for (int k = 0; k < 8; ++k) d = dot8_f16(A[k], B[k], d);

    float dot = d + __shfl_xor(d, 1, 64);   // bit-identical on both lanes

    // den is BIT-EXACT numpy: exact norms, mul then add (contract off).
    float prod = na * nb;
    float den  = prod + EPS_F;
    float sim  = dot / den;

    // Rigorous |sim_numpy - sim| bound:
    //   fp16 RNE inputs: 2*2^-11(1+eps) * sum|a_i b_i|  <=  9.8e-4 * na*nb  (C-S)
    //   fp32/dot2 accumulation both sides: <~ 1.5e-5 * na*nb
    //   -> 1.1e-3 * prod/den   (constants inflated ~10%)
    //   subnormal fp16 slack: 2^-25*sqrt(128)*(na+nb)/den  -> 4e-7 coef
    //   division/eval slack: +1e-6.  Degenerate rows (na==0, NaN/Inf) make
    //   sim/bnd NaN or bnd huge -> exact path (self-guarding).
    float bnd  = (1.1e-3f * prod + 4e-7f * (na + nb)) / den + 1e-6f;
    float diff = sim - THRESH;

    float keep;
    if (fabsf(diff) > bnd) {   // pair-uniform: both lanes bit-identical
        keep = (diff >= 0.f) ? 1.0f : 0.0f;
    } else {
        float inner = exact_inner_pairlanes(feat, src, dst, h);
        float se    = inner / den;          // exact numpy sim
        keep = (se >= THRESH) ? 1.0f : 0.0f;
    }

    if (h == 0) {
        float diag = (src == dst) ? 2.0f : 1.0f;
        out[pair] = (w[pair] * keep) * diag;
        int m = P + pair;
        if (m < E) {
            int s2 = ei[m];
            int d2 = ei[E + m];
            if (s2 == dst && d2 == src) out[m] = (w[m] * keep) * diag;  // exact mirror
            else                        out[m] = edge_out_scalar(feat, w[m], s2, d2);
        }
    }
}

extern "C" void kernel_launch(void* const* d_in, const int* in_sizes, int n_in,
                              void* d_out, int out_size, void* d_ws, size_t ws_size,
                              hipStream_t stream) {
    const int*   ei   = (const int*)d_in[0];     // [2, E] flattened (int32)
    const float* w    = (const float*)d_in[1];   // [E]
    const float* feat = (const float*)d_in[2];   // [N, 128]
    float*       out  = (float*)d_out;           // [E]

    int E = in_sizes[1];
    int P = E - E / 2;                 // ceil(E/2)
    long nfeat = in_sizes[2];
    long nNodes = nfeat / D_FEAT;
    size_t need = (size_t)nfeat * sizeof(__half) + (size_t)nNodes * sizeof(float);

    if (ws_size < need || (nfeat % D_FEAT) != 0) {
        int threads = 2 * P;
        int grid = (threads + 255) / 256;
        jaccard_edge_kernel<<<grid, 256, 0, stream>>>(ei, w, feat, out, P, E);
        return;
    }

    __half* hfeat = (__half*)d_ws;
    float*  nrm   = (float*)((char*)d_ws + (size_t)nfeat * sizeof(__half));

    int tA = 2 * (int)nNodes;
    norm_convert_kernel<<<(tA + 255) / 256, 256, 0, stream>>>(feat, hfeat, nrm, (int)nNodes);

    int tB = 2 * P;
    jaccard_edge_f16n_kernel<<<(tB + 255) / 256, 256, 0, stream>>>(
        ei, w, feat, hfeat, nrm, out, P, E);
}

// Round 4
// 157.618 us; speedup vs baseline: 1.0864x; 1.0864x over previous
//
#include <hip/hip_runtime.h>
#include <hip/hip_fp16.h>

#define D_FEAT 128
#define THRESH 0.01f
#define EPS_F  1e-8f

typedef _Float16 half2_t __attribute__((ext_vector_type(2)));

// ---------------------------------------------------------------------------
// Exact helpers: bit-exact replication of numpy's fp32 pipeline
// (8-accumulator pairwise sum). Proven absmax=0 in rounds 1-3.
// ---------------------------------------------------------------------------

// Fully-scalar exact path for one arbitrary edge (mirror-structure fallback).
__device__ float edge_out_scalar(const float* __restrict__ feat,
                                 float w, int s, int d) {
#pragma clang fp contract(off)
    const float* fs = feat + (size_t)s * D_FEAT;
    const float* fd = feat + (size_t)d * D_FEAT;
    float r[8], rs[8], rd[8];
#pragma unroll
    for (int j = 0; j < 8; ++j) {
        float a = fs[j], b = fd[j];
        r[j]  = a * b;
        rs[j] = a * a;
        rd[j] = b * b;
    }
    for (int k = 1; k < 16; ++k) {
#pragma unroll
        for (int j = 0; j < 8; ++j) {
            float a = fs[8 * k + j], b = fd[8 * k + j];
            r[j]  = r[j]  + a * b;
            rs[j] = rs[j] + a * a;
            rd[j] = rd[j] + b * b;
        }
    }
    float inner = ((r[0]  + r[1])  + (r[2]  + r[3]))  + ((r[4]  + r[5])  + (r[6]  + r[7]));
    float ss    = ((rs[0] + rs[1]) + (rs[2] + rs[3])) + ((rs[4] + rs[5]) + (rs[6] + rs[7]));
    float dd    = ((rd[0] + rd[1]) + (rd[2] + rd[3])) + ((rd[4] + rd[5]) + (rd[6] + rd[7]));
    float ns = __fsqrt_rn(ss);
    float nd = __fsqrt_rn(dd);
    float denom = ns * nd + EPS_F;
    float sim = inner / denom;
    float keep = (sim >= THRESH) ? 1.0f : 0.0f;
    float diag = (s == d) ? 2.0f : 1.0f;
    return (w * keep) * diag;
}

// Two-lane exact sim (dot + both norms): used by the ws-too-small fallback.
__device__ __forceinline__ float exact_sim_pairlanes(const float* __restrict__ feat,
                                                     int src, int dst, int h) {
#pragma clang fp contract(off)
    const float4* fs = (const float4*)(feat + (size_t)src * D_FEAT);
    const float4* fd = (const float4*)(feat + (size_t)dst * D_FEAT);
    float r[4], rs[4], rd[4];
    {
        float4 a = fs[h];
        float4 b = fd[h];
        r[0]  = a.x * b.x; r[1]  = a.y * b.y; r[2]  = a.z * b.z; r[3]  = a.w * b.w;
        rs[0] = a.x * a.x; rs[1] = a.y * a.y; rs[2] = a.z * a.z; rs[3] = a.w * a.w;
        rd[0] = b.x * b.x; rd[1] = b.y * b.y; rd[2] = b.z * b.z; rd[3] = b.w * b.w;
    }
#pragma unroll
    for (int k = 1; k < 16; ++k) {
        float4 a = fs[2 * k + h];
        float4 b = fd[2 * k + h];
        r[0]  = r[0]  + a.x * b.x;  r[1]  = r[1]  + a.y * b.y;
        r[2]  = r[2]  + a.z * b.z;  r[3]  = r[3]  + a.w * b.w;
        rs[0] = rs[0] + a.x * a.x;  rs[1] = rs[1] + a.y * a.y;
        rs[2] = rs[2] + a.z * a.z;  rs[3] = rs[3] + a.w * a.w;
        rd[0] = rd[0] + b.x * b.x;  rd[1] = rd[1] + b.y * b.y;
        rd[2] = rd[2] + b.z * b.z;  rd[3] = rd[3] + b.w * b.w;
    }
    float A  = (r[0]  + r[1])  + (r[2]  + r[3]);
    float As = (rs[0] + rs[1]) + (rs[2] + rs[3]);
    float Ad = (rd[0] + rd[1]) + (rd[2] + rd[3]);

    float inner = A  + __shfl_xor(A, 1, 64);
    float ssE   = As + __shfl_xor(As, 1, 64);
    float ddE   = Ad + __shfl_xor(Ad, 1, 64);

    float ns    = __fsqrt_rn(ssE);
    float nd    = __fsqrt_rn(ddE);
    float den   = ns * nd + EPS_F;
    return inner / den;
}

// Two-lane exact INNER only (norms come from the precomputed exact table).
// Uses shfl_xor(1): callers must place the cooperating lanes as xor-1 partners.
__device__ __forceinline__ float exact_inner_pairlanes(const float* __restrict__ feat,
                                                       int src, int dst, int h) {
#pragma clang fp contract(off)
    const float4* fs = (const float4*)(feat + (size_t)src * D_FEAT);
    const float4* fd = (const float4*)(feat + (size_t)dst * D_FEAT);
    float r[4];
    {
        float4 a = fs[h];
        float4 b = fd[h];
        r[0] = a.x * b.x; r[1] = a.y * b.y; r[2] = a.z * b.z; r[3] = a.w * b.w;
    }
#pragma unroll
    for (int k = 1; k < 16; ++k) {
        float4 a = fs[2 * k + h];
        float4 b = fd[2 * k + h];
        r[0] = r[0] + a.x * b.x;  r[1] = r[1] + a.y * b.y;
        r[2] = r[2] + a.z * b.z;  r[3] = r[3] + a.w * b.w;
    }
    float A = (r[0] + r[1]) + (r[2] + r[3]);
    return A + __shfl_xor(A, 1, 64);
}

// ---------------------------------------------------------------------------
// Fallback kernel (ws too small / odd feature count): round-1 proven path.
// ---------------------------------------------------------------------------
__global__ __launch_bounds__(256) void jaccard_edge_kernel(
    const int* __restrict__ ei, const float* __restrict__ w,
    const float* __restrict__ feat, float* __restrict__ out,
    int P, int E)
{
    int t    = blockIdx.x * blockDim.x + threadIdx.x;
    int pair = t >> 1;
    int half = t & 1;
    if (pair >= P) return;

    int src = ei[pair];
    int dst = ei[E + pair];

    float sim  = exact_sim_pairlanes(feat, src, dst, half);
    float keep = (sim >= THRESH) ? 1.0f : 0.0f;

    if (half == 0) {
        float diag = (src == dst) ? 2.0f : 1.0f;
        out[pair] = (w[pair] * keep) * diag;
        int m = P + pair;
        if (m < E) {
            int s2 = ei[m];
            int d2 = ei[E + m];
            if (s2 == dst && d2 == src) out[m] = (w[m] * keep) * diag;
            else                        out[m] = edge_out_scalar(feat, w[m], s2, d2);
        }
    }
}

// ---------------------------------------------------------------------------
// Pass A: EXACT numpy norm per node + pre-NORMALIZED fp16 row  u_hat = u/||u||.
// 2 lanes/node; lane h owns numpy accumulator classes [4h,4h+4) (chunk 2k+h),
// sequential k == numpy order; shfl_xor(1) final combine (IEEE-commutative).
// Rows with na<0.03 or non-finite are poisoned to NaN -> pass B exact path.
// ---------------------------------------------------------------------------
__global__ __launch_bounds__(256) void norm_convert_kernel(
    const float* __restrict__ feat, __half* __restrict__ hfeat,
    float* __restrict__ nrm, int nNodes)
{
#pragma clang fp contract(off)
    int t = blockIdx.x * blockDim.x + threadIdx.x;
    int node = t >> 1;
    int h    = t & 1;
    if (node >= nNodes) return;

    const float4* fs  = (const float4*)(feat + (size_t)node * D_FEAT);
    uint2*        hro = (uint2*)(hfeat + (size_t)node * D_FEAT);

    float4 row[16];
    float rs[4];
    {
        float4 a = fs[h];
        row[0] = a;
        rs[0] = a.x * a.x; rs[1] = a.y * a.y; rs[2] = a.z * a.z; rs[3] = a.w * a.w;
    }
#pragma unroll
    for (int k = 1; k < 16; ++k) {
        float4 a = fs[2 * k + h];
        row[k] = a;
        rs[0] = rs[0] + a.x * a.x;  rs[1] = rs[1] + a.y * a.y;
        rs[2] = rs[2] + a.z * a.z;  rs[3] = rs[3] + a.w * a.w;
    }
    float As = (rs[0] + rs[1]) + (rs[2] + rs[3]);
    float ss = As + __shfl_xor(As, 1, 64);
    float na = __fsqrt_rn(ss);
    if (h == 0) nrm[node] = na;    // exact numpy node_norm

    bool ok = isfinite(na) && (na >= 0.03f);
    float r = 1.0f / na;           // IEEE divide; both lanes identical

#pragma unroll
    for (int k = 0; k < 16; ++k) {
        uint2 o;
        if (ok) {
            float4 a = row[k];
            __half2 h0 = __floats2half2_rn(a.x * r, a.y * r);
            __half2 h1 = __floats2half2_rn(a.z * r, a.w * r);
            o.x = __builtin_bit_cast(unsigned int, h0);
            o.y = __builtin_bit_cast(unsigned int, h1);
        } else {
            o.x = 0x7FFF7FFFu;     // fp16 NaN pair -> forces exact path
            o.y = 0x7FFF7FFFu;
        }
        hro[2 * k + h] = o;
    }
}

// ---------------------------------------------------------------------------
// Pass B: quad layout (4 lanes/pair, 64B contiguous per instr per row — best
// measured fill pattern for 256B rows). Screen = fdot2(u_hat, v_hat) vs
// CONSTANT rigorous bound 1.2e-3 (derivation in round notes: element rounding
// 9.79e-4 + fdot2 acc 7.9e-6 + numpy-side 1.2e-6 + subnormal 7.6e-6 + EPS
// shift 1.3e-7, guarded by the NaN-poisoning for na<0.03). |dot|>=2 or NaN
// -> exact path (self-guarding). Borderline (~1.2%) -> exact fp32 numpy sim.
// ---------------------------------------------------------------------------
__device__ __forceinline__ float dot8_f16(uint4 ua, uint4 ub, float acc) {
    acc = __builtin_amdgcn_fdot2(__builtin_bit_cast(half2_t, ua.x),
                                 __builtin_bit_cast(half2_t, ub.x), acc, false);
    acc = __builtin_amdgcn_fdot2(__builtin_bit_cast(half2_t, ua.y),
                                 __builtin_bit_cast(half2_t, ub.y), acc, false);
    acc = __builtin_amdgcn_fdot2(__builtin_bit_cast(half2_t, ua.z),
                                 __builtin_bit_cast(half2_t, ub.z), acc, false);
    acc = __builtin_amdgcn_fdot2(__builtin_bit_cast(half2_t, ua.w),
                                 __builtin_bit_cast(half2_t, ub.w), acc, false);
    return acc;
}

__global__ __launch_bounds__(256) void jaccard_edge_f16u_kernel(
    const int* __restrict__ ei, const float* __restrict__ w,
    const float* __restrict__ feat, const __half* __restrict__ hfeat,
    const float* __restrict__ nrm, float* __restrict__ out, int P, int E)
{
#pragma clang fp contract(off)
    int t    = blockIdx.x * blockDim.x + threadIdx.x;
    int pair = t >> 2;
    int q    = t & 3;
    if (pair >= P) return;

    int src = __builtin_nontemporal_load(ei + pair);
    int dst = __builtin_nontemporal_load(ei + E + pair);

    const uint4* ha = (const uint4*)(hfeat + (size_t)src * D_FEAT);
    const uint4* hb = (const uint4*)(hfeat + (size_t)dst * D_FEAT);

    uint4 A[4], B[4];
#pragma unroll
    for (int k = 0; k < 4; ++k) {
        A[k] = ha[4 * k + q];
        B[k] = hb[4 * k + q];
    }

    float d = 0.f;
#pragma unroll
    for (int k = 0; k < 4; ++k) d = dot8_f16(A[k], B[k], d);

    // quad butterfly: bit-identical on all 4 lanes (IEEE a+b==b+a)
    d += __shfl_xor(d, 1, 64);
    float dot = d + __shfl_xor(d, 2, 64);

    float diff = dot - THRESH;
    const float bnd = 1.2e-3f;

    float keep;
    if (fabsf(diff) > bnd && fabsf(dot) < 2.0f) {   // quad-uniform decision
        keep = (diff >= 0.f) ? 1.0f : 0.0f;
    } else {
        // exact numpy sim: exact inner (fp32, numpy order) / exact denominator
        float se = 0.f;
        if (q < 2) {
            float inner = exact_inner_pairlanes(feat, src, dst, q);
            float den   = nrm[src] * nrm[dst] + EPS_F;   // mul then add
            se = inner / den;
        }
        keep = (se >= THRESH) ? 1.0f : 0.0f;   // valid on lane q==0 (writer)
    }

    if (q == 0) {
        float diag = (src == dst) ? 2.0f : 1.0f;
        __builtin_nontemporal_store((w[pair] * keep) * diag, out + pair);
        int m = P + pair;
        if (m < E) {
            int s2 = __builtin_nontemporal_load(ei + m);
            int d2 = __builtin_nontemporal_load(ei + E + m);
            if (s2 == dst && d2 == src) {
                __builtin_nontemporal_store((w[m] * keep) * diag, out + m);
            } else {
                out[m] = edge_out_scalar(feat, w[m], s2, d2);
            }
        }
    }
}

extern "C" void kernel_launch(void* const* d_in, const int* in_sizes, int n_in,
                              void* d_out, int out_size, void* d_ws, size_t ws_size,
                              hipStream_t stream) {
    const int*   ei   = (const int*)d_in[0];     // [2, E] flattened (int32)
    const float* w    = (const float*)d_in[1];   // [E]
    const float* feat = (const float*)d_in[2];   // [N, 128]
    float*       out  = (float*)d_out;           // [E]

    int E = in_sizes[1];
    int P = E - E / 2;                 // ceil(E/2)
    long nfeat = in_sizes[2];
    long nNodes = nfeat / D_FEAT;
    size_t need = (size_t)nfeat * sizeof(__half) + (size_t)nNodes * sizeof(float);

    if (ws_size < need || (nfeat % D_FEAT) != 0) {
        int threads = 2 * P;
        int grid = (threads + 255) / 256;
        jaccard_edge_kernel<<<grid, 256, 0, stream>>>(ei, w, feat, out, P, E);
        return;
    }

    __half* hfeat = (__half*)d_ws;
    float*  nrm   = (float*)((char*)d_ws + (size_t)nfeat * sizeof(__half));

    int tA = 2 * (int)nNodes;
    norm_convert_kernel<<<(tA + 255) / 256, 256, 0, stream>>>(feat, hfeat, nrm, (int)nNodes);

    int tB = 4 * P;
    jaccard_edge_f16u_kernel<<<(tB + 255) / 256, 256, 0, stream>>>(
        ei, w, feat, hfeat, nrm, out, P, E);
}

// Round 5
// 155.941 us; speedup vs baseline: 1.0981x; 1.0108x over previous
//
#include <hip/hip_runtime.h>
#include <hip/hip_fp16.h>

#define D_FEAT 128
#define THRESH 0.01f
#define EPS_F  1e-8f

typedef _Float16 half2_t __attribute__((ext_vector_type(2)));

// ---------------------------------------------------------------------------
// Exact helpers: bit-exact replication of numpy's fp32 pipeline
// (8-accumulator pairwise sum). Proven absmax=0 in rounds 1-4.
// ---------------------------------------------------------------------------

// Fully-scalar exact path for one arbitrary edge (mirror-structure fallback).
__device__ float edge_out_scalar(const float* __restrict__ feat,
                                 float w, int s, int d) {
#pragma clang fp contract(off)
    const float* fs = feat + (size_t)s * D_FEAT;
    const float* fd = feat + (size_t)d * D_FEAT;
    float r[8], rs[8], rd[8];
#pragma unroll
    for (int j = 0; j < 8; ++j) {
        float a = fs[j], b = fd[j];
        r[j]  = a * b;
        rs[j] = a * a;
        rd[j] = b * b;
    }
    for (int k = 1; k < 16; ++k) {
#pragma unroll
        for (int j = 0; j < 8; ++j) {
            float a = fs[8 * k + j], b = fd[8 * k + j];
            r[j]  = r[j]  + a * b;
            rs[j] = rs[j] + a * a;
            rd[j] = rd[j] + b * b;
        }
    }
    float inner = ((r[0]  + r[1])  + (r[2]  + r[3]))  + ((r[4]  + r[5])  + (r[6]  + r[7]));
    float ss    = ((rs[0] + rs[1]) + (rs[2] + rs[3])) + ((rs[4] + rs[5]) + (rs[6] + rs[7]));
    float dd    = ((rd[0] + rd[1]) + (rd[2] + rd[3])) + ((rd[4] + rd[5]) + (rd[6] + rd[7]));
    float ns = __fsqrt_rn(ss);
    float nd = __fsqrt_rn(dd);
    float denom = ns * nd + EPS_F;
    float sim = inner / denom;
    float keep = (sim >= THRESH) ? 1.0f : 0.0f;
    float diag = (s == d) ? 2.0f : 1.0f;
    return (w * keep) * diag;
}

// Two-lane exact sim (dot + both norms): used by the ws-too-small fallback.
__device__ __forceinline__ float exact_sim_pairlanes(const float* __restrict__ feat,
                                                     int src, int dst, int h) {
#pragma clang fp contract(off)
    const float4* fs = (const float4*)(feat + (size_t)src * D_FEAT);
    const float4* fd = (const float4*)(feat + (size_t)dst * D_FEAT);
    float r[4], rs[4], rd[4];
    {
        float4 a = fs[h];
        float4 b = fd[h];
        r[0]  = a.x * b.x; r[1]  = a.y * b.y; r[2]  = a.z * b.z; r[3]  = a.w * b.w;
        rs[0] = a.x * a.x; rs[1] = a.y * a.y; rs[2] = a.z * a.z; rs[3] = a.w * a.w;
        rd[0] = b.x * b.x; rd[1] = b.y * b.y; rd[2] = b.z * b.z; rd[3] = b.w * b.w;
    }
#pragma unroll
    for (int k = 1; k < 16; ++k) {
        float4 a = fs[2 * k + h];
        float4 b = fd[2 * k + h];
        r[0]  = r[0]  + a.x * b.x;  r[1]  = r[1]  + a.y * b.y;
        r[2]  = r[2]  + a.z * b.z;  r[3]  = r[3]  + a.w * b.w;
        rs[0] = rs[0] + a.x * a.x;  rs[1] = rs[1] + a.y * a.y;
        rs[2] = rs[2] + a.z * a.z;  rs[3] = rs[3] + a.w * a.w;
        rd[0] = rd[0] + b.x * b.x;  rd[1] = rd[1] + b.y * b.y;
        rd[2] = rd[2] + b.z * b.z;  rd[3] = rd[3] + b.w * b.w;
    }
    float A  = (r[0]  + r[1])  + (r[2]  + r[3]);
    float As = (rs[0] + rs[1]) + (rs[2] + rs[3]);
    float Ad = (rd[0] + rd[1]) + (rd[2] + rd[3]);

    float inner = A  + __shfl_xor(A, 1, 64);
    float ssE   = As + __shfl_xor(As, 1, 64);
    float ddE   = Ad + __shfl_xor(Ad, 1, 64);

    float ns    = __fsqrt_rn(ssE);
    float nd    = __fsqrt_rn(ddE);
    float den   = ns * nd + EPS_F;
    return inner / den;
}

// Two-lane exact INNER only (norms come from the precomputed exact table).
// Uses shfl_xor(1): cooperating lanes must be xor-1 partners.
__device__ __forceinline__ float exact_inner_pairlanes(const float* __restrict__ feat,
                                                       int src, int dst, int h) {
#pragma clang fp contract(off)
    const float4* fs = (const float4*)(feat + (size_t)src * D_FEAT);
    const float4* fd = (const float4*)(feat + (size_t)dst * D_FEAT);
    float r[4];
    {
        float4 a = fs[h];
        float4 b = fd[h];
        r[0] = a.x * b.x; r[1] = a.y * b.y; r[2] = a.z * b.z; r[3] = a.w * b.w;
    }
#pragma unroll
    for (int k = 1; k < 16; ++k) {
        float4 a = fs[2 * k + h];
        float4 b = fd[2 * k + h];
        r[0] = r[0] + a.x * b.x;  r[1] = r[1] + a.y * b.y;
        r[2] = r[2] + a.z * b.z;  r[3] = r[3] + a.w * b.w;
    }
    float A = (r[0] + r[1]) + (r[2] + r[3]);
    return A + __shfl_xor(A, 1, 64);
}

// ---------------------------------------------------------------------------
// Fallback kernel (ws too small / odd feature count): round-1 proven path.
// ---------------------------------------------------------------------------
__global__ __launch_bounds__(256) void jaccard_edge_kernel(
    const int* __restrict__ ei, const float* __restrict__ w,
    const float* __restrict__ feat, float* __restrict__ out,
    int P, int E)
{
    int t    = blockIdx.x * blockDim.x + threadIdx.x;
    int pair = t >> 1;
    int half = t & 1;
    if (pair >= P) return;

    int src = ei[pair];
    int dst = ei[E + pair];

    float sim  = exact_sim_pairlanes(feat, src, dst, half);
    float keep = (sim >= THRESH) ? 1.0f : 0.0f;

    if (half == 0) {
        float diag = (src == dst) ? 2.0f : 1.0f;
        out[pair] = (w[pair] * keep) * diag;
        int m = P + pair;
        if (m < E) {
            int s2 = ei[m];
            int d2 = ei[E + m];
            if (s2 == dst && d2 == src) out[m] = (w[m] * keep) * diag;
            else                        out[m] = edge_out_scalar(feat, w[m], s2, d2);
        }
    }
}

// ---------------------------------------------------------------------------
// Pass A v2: EXACT numpy norm + pre-normalized fp16 row, 4 lanes/node.
// Lane q owns numpy accumulator classes {2q, 2q+1}: element 8k+2q is float2
// at float2-index 4k+q -> per k the quad reads 32B contiguous. Sequential k
// == numpy accumulation order. Combine: s_q = r[2q]+r[2q+1] in-lane, then
// shfl_xor(1) -> (s0+s1),(s2+s3); shfl_xor(2) -> full numpy pairwise tree,
// bit-identical on all 4 lanes (IEEE commutativity). Buffer = 32 VGPRs.
// Rows with na<0.03 or non-finite are poisoned to NaN -> pass B exact path.
// ---------------------------------------------------------------------------
__global__ __launch_bounds__(256) void norm_convert_kernel(
    const float* __restrict__ feat, __half* __restrict__ hfeat,
    float* __restrict__ nrm, int nNodes)
{
#pragma clang fp contract(off)
    int t    = blockIdx.x * blockDim.x + threadIdx.x;
    int node = t >> 2;
    int q    = t & 3;
    if (node >= nNodes) return;

    const float2* fs  = (const float2*)(feat + (size_t)node * D_FEAT);
    unsigned*     hro = (unsigned*)(hfeat + (size_t)node * D_FEAT);

    float2 row[16];
    float r0, r1;
    {
        float2 a = fs[q];
        row[0] = a;
        r0 = a.x * a.x;
        r1 = a.y * a.y;
    }
#pragma unroll
    for (int k = 1; k < 16; ++k) {
        float2 a = fs[4 * k + q];
        row[k] = a;
        r0 = r0 + a.x * a.x;
        r1 = r1 + a.y * a.y;
    }
    float s  = r0 + r1;                 // r[2q] + r[2q+1]
    float ss = s + __shfl_xor(s, 1, 64);   // (s0+s1) | (s2+s3)
    ss       = ss + __shfl_xor(ss, 2, 64); // full numpy tree, all lanes equal
    float na = __fsqrt_rn(ss);
    if (q == 0) nrm[node] = na;         // exact numpy node_norm

    bool ok = isfinite(na) && (na >= 0.03f);
    float r = 1.0f / na;                // identical on all 4 lanes

#pragma unroll
    for (int k = 0; k < 16; ++k) {
        unsigned o;
        if (ok) {
            float2 a = row[k];
            __half2 hv = __floats2half2_rn(a.x * r, a.y * r);
            o = __builtin_bit_cast(unsigned, hv);
        } else {
            o = 0x7FFF7FFFu;            // fp16 NaN pair -> forces exact path
        }
        hro[4 * k + q] = o;
    }
}

// ---------------------------------------------------------------------------
// Pass B: quad layout (4 lanes/pair, 64B contiguous per instr per row — best
// measured fill pattern). Screen = fdot2(u_hat, v_hat) vs CONSTANT rigorous
// bound 1.2e-3 (element rounding 9.79e-4 + fdot2 acc 7.9e-6 + numpy-side
// 1.2e-6 + subnormal 7.6e-6 + EPS shift 1.3e-7; na<0.03 rows NaN-poisoned).
// |dot|>=2 or NaN -> exact path (self-guarding). Borderline (~1.2%) -> exact
// fp32 numpy sim. Mirror/weight stream loads hoisted above the gather loop
// so their latency hides under the feature gathers.
// ---------------------------------------------------------------------------
__device__ __forceinline__ float dot8_f16(uint4 ua, uint4 ub, float acc) {
    acc = __builtin_amdgcn_fdot2(__builtin_bit_cast(half2_t, ua.x),
                                 __builtin_bit_cast(half2_t, ub.x), acc, false);
    acc = __builtin_amdgcn_fdot2(__builtin_bit_cast(half2_t, ua.y),
                                 __builtin_bit_cast(half2_t, ub.y), acc, false);
    acc = __builtin_amdgcn_fdot2(__builtin_bit_cast(half2_t, ua.z),
                                 __builtin_bit_cast(half2_t, ub.z), acc, false);
    acc = __builtin_amdgcn_fdot2(__builtin_bit_cast(half2_t, ua.w),
                                 __builtin_bit_cast(half2_t, ub.w), acc, false);
    return acc;
}

__global__ __launch_bounds__(256) void jaccard_edge_f16u_kernel(
    const int* __restrict__ ei, const float* __restrict__ w,
    const float* __restrict__ feat, const __half* __restrict__ hfeat,
    const float* __restrict__ nrm, float* __restrict__ out, int P, int E)
{
#pragma clang fp contract(off)
    int t    = blockIdx.x * blockDim.x + threadIdx.x;
    int pair = t >> 2;
    int q    = t & 3;
    if (pair >= P) return;

    int src = __builtin_nontemporal_load(ei + pair);
    int dst = __builtin_nontemporal_load(ei + E + pair);

    // Hoisted single-use streams (coalesced; latency hidden under gathers).
    float wp  = __builtin_nontemporal_load(w + pair);
    int   m   = P + pair;
    bool  hasm = (m < E);
    int s2 = 0, d2 = 0;
    float wm = 0.f;
    if (hasm) {
        s2 = __builtin_nontemporal_load(ei + m);
        d2 = __builtin_nontemporal_load(ei + E + m);
        wm = __builtin_nontemporal_load(w + m);
    }

    const uint4* ha = (const uint4*)(hfeat + (size_t)src * D_FEAT);
    const uint4* hb = (const uint4*)(hfeat + (size_t)dst * D_FEAT);

    uint4 A[4], B[4];
#pragma unroll
    for (int k = 0; k < 4; ++k) {
        A[k] = ha[4 * k + q];
        B[k] = hb[4 * k + q];
    }

    float d = 0.f;
#pragma unroll
    for (int k = 0; k < 4; ++k) d = dot8_f16(A[k], B[k], d);

    // quad butterfly: bit-identical on all 4 lanes (IEEE a+b==b+a)
    d += __shfl_xor(d, 1, 64);
    float dot = d + __shfl_xor(d, 2, 64);

    float diff = dot - THRESH;
    const float bnd = 1.2e-3f;

    float keep;
    if (fabsf(diff) > bnd && fabsf(dot) < 2.0f) {   // quad-uniform decision
        keep = (diff >= 0.f) ? 1.0f : 0.0f;
    } else {
        // exact numpy sim: exact inner (fp32, numpy order) / exact denominator
        float se = 0.f;
        if (q < 2) {
            float inner = exact_inner_pairlanes(feat, src, dst, q);
            float den   = nrm[src] * nrm[dst] + EPS_F;   // mul then add
            se = inner / den;
        }
        keep = (se >= THRESH) ? 1.0f : 0.0f;   // valid on lane q==0 (writer)
    }

    if (q == 0) {
        float diag = (src == dst) ? 2.0f : 1.0f;
        __builtin_nontemporal_store((wp * keep) * diag, out + pair);
        if (hasm) {
            if (s2 == dst && d2 == src) {
                __builtin_nontemporal_store((wm * keep) * diag, out + m);
            } else {
                out[m] = edge_out_scalar(feat, wm, s2, d2);
            }
        }
    }
}

extern "C" void kernel_launch(void* const* d_in, const int* in_sizes, int n_in,
                              void* d_out, int out_size, void* d_ws, size_t ws_size,
                              hipStream_t stream) {
    const int*   ei   = (const int*)d_in[0];     // [2, E] flattened (int32)
    const float* w    = (const float*)d_in[1];   // [E]
    const float* feat = (const float*)d_in[2];   // [N, 128]
    float*       out  = (float*)d_out;           // [E]

    int E = in_sizes[1];
    int P = E - E / 2;                 // ceil(E/2)
    long nfeat = in_sizes[2];
    long nNodes = nfeat / D_FEAT;
    size_t need = (size_t)nfeat * sizeof(__half) + (size_t)nNodes * sizeof(float);

    if (ws_size < need || (nfeat % D_FEAT) != 0) {
        int threads = 2 * P;
        int grid = (threads + 255) / 256;
        jaccard_edge_kernel<<<grid, 256, 0, stream>>>(ei, w, feat, out, P, E);
        return;
    }

    __half* hfeat = (__half*)d_ws;
    float*  nrm   = (float*)((char*)d_ws + (size_t)nfeat * sizeof(__half));

    int tA = 4 * (int)nNodes;
    norm_convert_kernel<<<(tA + 255) / 256, 256, 0, stream>>>(feat, hfeat, nrm, (int)nNodes);

    int tB = 4 * P;
    jaccard_edge_f16u_kernel<<<(tB + 255) / 256, 256, 0, stream>>>(
        ei, w, feat, hfeat, nrm, out, P, E);
}

// Round 6
// 152.506 us; speedup vs baseline: 1.1229x; 1.0225x over previous
//
#include <hip/hip_runtime.h>
#include <hip/hip_fp16.h>

#define D_FEAT 128
#define THRESH 0.01f
#define EPS_F  1e-8f

#define NPB 64          // nodes per block in pass A
#define ROWF 132        // padded row stride in floats (128 + 16B pad)

typedef _Float16 half2_t __attribute__((ext_vector_type(2)));

// ---------------------------------------------------------------------------
// Exact helpers: bit-exact replication of numpy's fp32 pipeline
// (8-accumulator pairwise sum). Proven absmax=0 in rounds 1-5.
// ---------------------------------------------------------------------------

// Fully-scalar exact path for one arbitrary edge (mirror-structure fallback).
__device__ float edge_out_scalar(const float* __restrict__ feat,
                                 float w, int s, int d) {
#pragma clang fp contract(off)
    const float* fs = feat + (size_t)s * D_FEAT;
    const float* fd = feat + (size_t)d * D_FEAT;
    float r[8], rs[8], rd[8];
#pragma unroll
    for (int j = 0; j < 8; ++j) {
        float a = fs[j], b = fd[j];
        r[j]  = a * b;
        rs[j] = a * a;
        rd[j] = b * b;
    }
    for (int k = 1; k < 16; ++k) {
#pragma unroll
        for (int j = 0; j < 8; ++j) {
            float a = fs[8 * k + j], b = fd[8 * k + j];
            r[j]  = r[j]  + a * b;
            rs[j] = rs[j] + a * a;
            rd[j] = rd[j] + b * b;
        }
    }
    float inner = ((r[0]  + r[1])  + (r[2]  + r[3]))  + ((r[4]  + r[5])  + (r[6]  + r[7]));
    float ss    = ((rs[0] + rs[1]) + (rs[2] + rs[3])) + ((rs[4] + rs[5]) + (rs[6] + rs[7]));
    float dd    = ((rd[0] + rd[1]) + (rd[2] + rd[3])) + ((rd[4] + rd[5]) + (rd[6] + rd[7]));
    float ns = __fsqrt_rn(ss);
    float nd = __fsqrt_rn(dd);
    float denom = ns * nd + EPS_F;
    float sim = inner / denom;
    float keep = (sim >= THRESH) ? 1.0f : 0.0f;
    float diag = (s == d) ? 2.0f : 1.0f;
    return (w * keep) * diag;
}

// Two-lane exact sim (dot + both norms): used by the ws-too-small fallback.
__device__ __forceinline__ float exact_sim_pairlanes(const float* __restrict__ feat,
                                                     int src, int dst, int h) {
#pragma clang fp contract(off)
    const float4* fs = (const float4*)(feat + (size_t)src * D_FEAT);
    const float4* fd = (const float4*)(feat + (size_t)dst * D_FEAT);
    float r[4], rs[4], rd[4];
    {
        float4 a = fs[h];
        float4 b = fd[h];
        r[0]  = a.x * b.x; r[1]  = a.y * b.y; r[2]  = a.z * b.z; r[3]  = a.w * b.w;
        rs[0] = a.x * a.x; rs[1] = a.y * a.y; rs[2] = a.z * a.z; rs[3] = a.w * a.w;
        rd[0] = b.x * b.x; rd[1] = b.y * b.y; rd[2] = b.z * b.z; rd[3] = b.w * b.w;
    }
#pragma unroll
    for (int k = 1; k < 16; ++k) {
        float4 a = fs[2 * k + h];
        float4 b = fd[2 * k + h];
        r[0]  = r[0]  + a.x * b.x;  r[1]  = r[1]  + a.y * b.y;
        r[2]  = r[2]  + a.z * b.z;  r[3]  = r[3]  + a.w * b.w;
        rs[0] = rs[0] + a.x * a.x;  rs[1] = rs[1] + a.y * a.y;
        rs[2] = rs[2] + a.z * a.z;  rs[3] = rs[3] + a.w * a.w;
        rd[0] = rd[0] + b.x * b.x;  rd[1] = rd[1] + b.y * b.y;
        rd[2] = rd[2] + b.z * b.z;  rd[3] = rd[3] + b.w * b.w;
    }
    float A  = (r[0]  + r[1])  + (r[2]  + r[3]);
    float As = (rs[0] + rs[1]) + (rs[2] + rs[3]);
    float Ad = (rd[0] + rd[1]) + (rd[2] + rd[3]);

    float inner = A  + __shfl_xor(A, 1, 64);
    float ssE   = As + __shfl_xor(As, 1, 64);
    float ddE   = Ad + __shfl_xor(Ad, 1, 64);

    float ns    = __fsqrt_rn(ssE);
    float nd    = __fsqrt_rn(ddE);
    float den   = ns * nd + EPS_F;
    return inner / den;
}

// Two-lane exact INNER only (norms come from the precomputed exact table).
// Uses shfl_xor(1): cooperating lanes must be xor-1 partners.
__device__ __forceinline__ float exact_inner_pairlanes(const float* __restrict__ feat,
                                                       int src, int dst, int h) {
#pragma clang fp contract(off)
    const float4* fs = (const float4*)(feat + (size_t)src * D_FEAT);
    const float4* fd = (const float4*)(feat + (size_t)dst * D_FEAT);
    float r[4];
    {
        float4 a = fs[h];
        float4 b = fd[h];
        r[0] = a.x * b.x; r[1] = a.y * b.y; r[2] = a.z * b.z; r[3] = a.w * b.w;
    }
#pragma unroll
    for (int k = 1; k < 16; ++k) {
        float4 a = fs[2 * k + h];
        float4 b = fd[2 * k + h];
        r[0] = r[0] + a.x * b.x;  r[1] = r[1] + a.y * b.y;
        r[2] = r[2] + a.z * b.z;  r[3] = r[3] + a.w * b.w;
    }
    float A = (r[0] + r[1]) + (r[2] + r[3]);
    return A + __shfl_xor(A, 1, 64);
}

// ---------------------------------------------------------------------------
// Fallback kernel (ws too small / odd feature count): round-1 proven path.
// ---------------------------------------------------------------------------
__global__ __launch_bounds__(256) void jaccard_edge_kernel(
    const int* __restrict__ ei, const float* __restrict__ w,
    const float* __restrict__ feat, float* __restrict__ out,
    int P, int E)
{
    int t    = blockIdx.x * blockDim.x + threadIdx.x;
    int pair = t >> 1;
    int half = t & 1;
    if (pair >= P) return;

    int src = ei[pair];
    int dst = ei[E + pair];

    float sim  = exact_sim_pairlanes(feat, src, dst, half);
    float keep = (sim >= THRESH) ? 1.0f : 0.0f;

    if (half == 0) {
        float diag = (src == dst) ? 2.0f : 1.0f;
        out[pair] = (w[pair] * keep) * diag;
        int m = P + pair;
        if (m < E) {
            int s2 = ei[m];
            int d2 = ei[E + m];
            if (s2 == dst && d2 == src) out[m] = (w[m] * keep) * diag;
            else                        out[m] = edge_out_scalar(feat, w[m], s2, d2);
        }
    }
}

// ---------------------------------------------------------------------------
// Pass A v3: LDS-staged. Per block: 64 nodes.
//  Phase 1: global float4 -> LDS, fully coalesced (1 KB/wave/instr).
//  Phase 2: exact numpy norm from LDS, 4 lanes/node, lane q owns accumulator
//           classes {2q,2q+1} (element 8k+2q = float2 index 4k+q), sequential
//           k == numpy order; shfl_xor(1) then (2) == numpy pairwise tree
//           (IEEE-commutative, bit-identical on all 4 lanes). LDS values are
//           bit-identical copies of global -> exactness preserved.
//           Bad rows (na<0.03 / non-finite) poison r=NaN -> NaN fp16 row ->
//           pass B exact path (self-guarding).
//  Phase 3: normalize+convert from LDS, fully-coalesced uint4 stores.
// Row stride padded to 132 floats (16 B) to break power-of-2 bank strides.
// ---------------------------------------------------------------------------
__global__ __launch_bounds__(256) void norm_convert_kernel(
    const float* __restrict__ feat, __half* __restrict__ hfeat,
    float* __restrict__ nrm, int nNodes)
{
#pragma clang fp contract(off)
    __shared__ float lds[NPB * ROWF];
    __shared__ float lr[NPB];

    int block0 = blockIdx.x * NPB;
    int nvalid = nNodes - block0; if (nvalid > NPB) nvalid = NPB;
    int tid = threadIdx.x;

    // Phase 1: coalesced global -> LDS
    const float4* gsrc = (const float4*)(feat + (size_t)block0 * D_FEAT);
    float4* lds4 = (float4*)lds;
    int nf4 = nvalid * (D_FEAT / 4);          // 32 float4 per node
    for (int i = tid; i < nf4; i += 256) {
        int n = i >> 5, c = i & 31;
        lds4[n * (ROWF / 4) + c] = gsrc[i];
    }
    __syncthreads();

    // Phase 2: exact numpy norm (4 lanes/node)
    int ln = tid >> 2, q = tid & 3;
    if (ln < nvalid) {
        const float2* lrow = (const float2*)(lds + ln * ROWF);
        float2 a = lrow[q];
        float r0 = a.x * a.x, r1 = a.y * a.y;
#pragma unroll
        for (int k = 1; k < 16; ++k) {
            float2 v = lrow[4 * k + q];
            r0 = r0 + v.x * v.x;
            r1 = r1 + v.y * v.y;
        }
        float s  = r0 + r1;                     // r[2q] + r[2q+1]
        float ss = s + __shfl_xor(s, 1, 64);    // (s0+s1) | (s2+s3)
        ss       = ss + __shfl_xor(ss, 2, 64);  // full numpy tree
        float na = __fsqrt_rn(ss);
        if (q == 0) {
            nrm[block0 + ln] = na;              // exact numpy node_norm
            bool ok = isfinite(na) && (na >= 0.03f);
            lr[ln] = ok ? (1.0f / na) : __builtin_nanf("");
        }
    }
    __syncthreads();

    // Phase 3: normalize + fp16 convert, coalesced uint4 stores
    uint4* gdst = (uint4*)(hfeat + (size_t)block0 * D_FEAT);
    int nu4 = nvalid * (D_FEAT / 8);           // 16 uint4 per node
    for (int i = tid; i < nu4; i += 256) {
        int n = i >> 4, c = i & 15;
        float r = lr[n];
        const float4* lp = (const float4*)(lds + n * ROWF + 8 * c);
        float4 x = lp[0], y = lp[1];
        __half2 h0 = __floats2half2_rn(x.x * r, x.y * r);
        __half2 h1 = __floats2half2_rn(x.z * r, x.w * r);
        __half2 h2 = __floats2half2_rn(y.x * r, y.y * r);
        __half2 h3 = __floats2half2_rn(y.z * r, y.w * r);
        uint4 o;
        o.x = __builtin_bit_cast(unsigned, h0);
        o.y = __builtin_bit_cast(unsigned, h1);
        o.z = __builtin_bit_cast(unsigned, h2);
        o.w = __builtin_bit_cast(unsigned, h3);
        gdst[i] = o;
    }
}

// ---------------------------------------------------------------------------
// Pass B: quad layout (4 lanes/pair, 64B contiguous per instr per row — best
// measured fill pattern, 3.53 TB/s). Screen = fdot2(u_hat, v_hat) vs CONSTANT
// rigorous bound 1.2e-3 (element rounding 9.79e-4 + fdot2 acc 7.9e-6 +
// numpy-side 1.2e-6 + subnormal 7.6e-6 + EPS shift 1.3e-7; na<0.03 rows
// NaN-poisoned). |dot|>=2 or NaN -> exact path. Borderline (~1.2%) -> exact
// fp32 numpy sim. Single-use streams hoisted above the gathers.
// ---------------------------------------------------------------------------
__device__ __forceinline__ float dot8_f16(uint4 ua, uint4 ub, float acc) {
    acc = __builtin_amdgcn_fdot2(__builtin_bit_cast(half2_t, ua.x),
                                 __builtin_bit_cast(half2_t, ub.x), acc, false);
    acc = __builtin_amdgcn_fdot2(__builtin_bit_cast(half2_t, ua.y),
                                 __builtin_bit_cast(half2_t, ub.y), acc, false);
    acc = __builtin_amdgcn_fdot2(__builtin_bit_cast(half2_t, ua.z),
                                 __builtin_bit_cast(half2_t, ub.z), acc, false);
    acc = __builtin_amdgcn_fdot2(__builtin_bit_cast(half2_t, ua.w),
                                 __builtin_bit_cast(half2_t, ub.w), acc, false);
    return acc;
}

__global__ __launch_bounds__(256) void jaccard_edge_f16u_kernel(
    const int* __restrict__ ei, const float* __restrict__ w,
    const float* __restrict__ feat, const __half* __restrict__ hfeat,
    const float* __restrict__ nrm, float* __restrict__ out, int P, int E)
{
#pragma clang fp contract(off)
    int t    = blockIdx.x * blockDim.x + threadIdx.x;
    int pair = t >> 2;
    int q    = t & 3;
    if (pair >= P) return;

    int src = __builtin_nontemporal_load(ei + pair);
    int dst = __builtin_nontemporal_load(ei + E + pair);

    // Hoisted single-use streams (coalesced; latency hidden under gathers).
    float wp  = __builtin_nontemporal_load(w + pair);
    int   m   = P + pair;
    bool  hasm = (m < E);
    int s2 = 0, d2 = 0;
    float wm = 0.f;
    if (hasm) {
        s2 = __builtin_nontemporal_load(ei + m);
        d2 = __builtin_nontemporal_load(ei + E + m);
        wm = __builtin_nontemporal_load(w + m);
    }

    const uint4* ha = (const uint4*)(hfeat + (size_t)src * D_FEAT);
    const uint4* hb = (const uint4*)(hfeat + (size_t)dst * D_FEAT);

    uint4 A[4], B[4];
#pragma unroll
    for (int k = 0; k < 4; ++k) {
        A[k] = ha[4 * k + q];
        B[k] = hb[4 * k + q];
    }

    float d = 0.f;
#pragma unroll
    for (int k = 0; k < 4; ++k) d = dot8_f16(A[k], B[k], d);

    // quad butterfly: bit-identical on all 4 lanes (IEEE a+b==b+a)
    d += __shfl_xor(d, 1, 64);
    float dot = d + __shfl_xor(d, 2, 64);

    float diff = dot - THRESH;
    const float bnd = 1.2e-3f;

    float keep;
    if (fabsf(diff) > bnd && fabsf(dot) < 2.0f) {   // quad-uniform decision
        keep = (diff >= 0.f) ? 1.0f : 0.0f;
    } else {
        // exact numpy sim: exact inner (fp32, numpy order) / exact denominator
        float se = 0.f;
        if (q < 2) {
            float inner = exact_inner_pairlanes(feat, src, dst, q);
            float den   = nrm[src] * nrm[dst] + EPS_F;   // mul then add
            se = inner / den;
        }
        keep = (se >= THRESH) ? 1.0f : 0.0f;   // valid on lane q==0 (writer)
    }

    if (q == 0) {
        float diag = (src == dst) ? 2.0f : 1.0f;
        __builtin_nontemporal_store((wp * keep) * diag, out + pair);
        if (hasm) {
            if (s2 == dst && d2 == src) {
                __builtin_nontemporal_store((wm * keep) * diag, out + m);
            } else {
                out[m] = edge_out_scalar(feat, wm, s2, d2);
            }
        }
    }
}

extern "C" void kernel_launch(void* const* d_in, const int* in_sizes, int n_in,
                              void* d_out, int out_size, void* d_ws, size_t ws_size,
                              hipStream_t stream) {
    const int*   ei   = (const int*)d_in[0];     // [2, E] flattened (int32)
    const float* w    = (const float*)d_in[1];   // [E]
    const float* feat = (const float*)d_in[2];   // [N, 128]
    float*       out  = (float*)d_out;           // [E]

    int E = in_sizes[1];
    int P = E - E / 2;                 // ceil(E/2)
    long nfeat = in_sizes[2];
    long nNodes = nfeat / D_FEAT;
    size_t need = (size_t)nfeat * sizeof(__half) + (size_t)nNodes * sizeof(float);

    if (ws_size < need || (nfeat % D_FEAT) != 0) {
        int threads = 2 * P;
        int grid = (threads + 255) / 256;
        jaccard_edge_kernel<<<grid, 256, 0, stream>>>(ei, w, feat, out, P, E);
        return;
    }

    __half* hfeat = (__half*)d_ws;
    float*  nrm   = (float*)((char*)d_ws + (size_t)nfeat * sizeof(__half));

    int gridA = (int)((nNodes + NPB - 1) / NPB);
    norm_convert_kernel<<<gridA, 256, 0, stream>>>(feat, hfeat, nrm, (int)nNodes);

    int tB = 4 * P;
    jaccard_edge_f16u_kernel<<<(tB + 255) / 256, 256, 0, stream>>>(
        ei, w, feat, hfeat, nrm, out, P, E);
}